// Round 3
// baseline (2034.102 us; speedup 1.0000x reference)
//
#include <hip/hip_runtime.h>
#include <cstdint>
#include <cstddef>

#define NPTS   262144
#define NNB    16
#define NKP    15
#define CIN    128
#define D2     64
#define COUT   256
#define PINF   0.04f
#define NSLOPE 0.2f
#define BEPS   1e-5f

// ---------------- workspace layout (float element offsets) ----------------
#define WS_BN1_SUM  0            // 64
#define WS_BN1_SQ   64           // 64
#define WS_KP_SUM   128          // 64
#define WS_KP_SQ    192          // 64
#define WS_U2_DSUM  256          // 256
#define WS_U2_DSQ   512          // 256
#define WS_PAIRCNT  768          // 1 int
#define WS_PTCNT    769          // 1 int
#define WS_FLAGS    1024         // NPTS ints
#define WS_PLIST    (1024 + NPTS)                      // NPTS ints (active point ids)
#define WS_ZERO_END WS_PLIST                           // zero [0, WS_PLIST)
#define WS_HPRE     (WS_PLIST + NPTS)                  // NPTS*64 floats
#define WS_KPPRE    (WS_HPRE + (size_t)NPTS * D2)      // NPTS*64 floats (active rows zeroed by k3c)
#define WS_DERIV    (WS_KPPRE + (size_t)NPTS * D2)     // 2048 floats
#define D_S1   0
#define D_T1   64
#define D_SKP  128
#define D_TKP  192
#define D_ZB   256
#define D_S2   320
#define D_T2   576
#define D_BU2  832
#define D_FB   1088
#define WS_PAIRS    (WS_DERIV + 2048)                  // int2 per pair

__device__ __forceinline__ float lrelu(float v) { return v >= 0.f ? v : NSLOPE * v; }

// ---------------- k0: zero stats/counters/flags (~1 MB) ----------------
__global__ void k0_zero(float* __restrict__ ws) {
  size_t n4 = WS_ZERO_END / 4;
  float4 z = make_float4(0.f, 0.f, 0.f, 0.f);
  for (size_t i = (size_t)blockIdx.x * blockDim.x + threadIdx.x; i < n4;
       i += (size_t)gridDim.x * blockDim.x)
    ((float4*)ws)[i] = z;
}

// ---------------- k1: fused GEMM  [h_pre | sc] = x @ [W1 | Wsc], + BN1 stats --
__global__ __launch_bounds__(256) void k1_gemm(const float* __restrict__ x,
                                               const float* __restrict__ W1,
                                               const float* __restrict__ Wsc,
                                               float* __restrict__ hpre,
                                               float* __restrict__ outp,
                                               float* __restrict__ ws) {
  __shared__ __align__(16) float As[32][72];
  __shared__ __align__(16) float Bs[5][32][64];
  __shared__ float cs[16][68];
  const int t = threadIdx.x;
  const int row0 = blockIdx.x * 64;
  const int tx = t & 15, ty = t >> 4;
  float acc[5][4][4];
#pragma unroll
  for (int j5 = 0; j5 < 5; j5++)
#pragma unroll
    for (int i = 0; i < 4; i++)
#pragma unroll
      for (int j = 0; j < 4; j++) acc[j5][i][j] = 0.f;

  for (int k0 = 0; k0 < CIN; k0 += 32) {
    __syncthreads();
    {
      int r = t >> 2;
      int c = (t & 3) * 8;
      const float* src = &x[(size_t)(row0 + r) * CIN + k0 + c];
      float4 a0 = *(const float4*)src;
      float4 a1 = *(const float4*)(src + 4);
      As[c + 0][r] = a0.x; As[c + 1][r] = a0.y; As[c + 2][r] = a0.z; As[c + 3][r] = a0.w;
      As[c + 4][r] = a1.x; As[c + 5][r] = a1.y; As[c + 6][r] = a1.z; As[c + 7][r] = a1.w;
    }
    {
      int kk = t >> 3;
      int c = (t & 7) * 8;
#pragma unroll
      for (int j5 = 0; j5 < 5; j5++) {
        const float* B = (j5 == 0) ? &W1[(size_t)(k0 + kk) * D2 + c]
                                   : &Wsc[(size_t)(k0 + kk) * COUT + (j5 - 1) * 64 + c];
        float4 b0 = *(const float4*)B;
        float4 b1 = *(const float4*)(B + 4);
        *(float4*)&Bs[j5][kk][c] = b0;
        *(float4*)&Bs[j5][kk][c + 4] = b1;
      }
    }
    __syncthreads();
#pragma unroll
    for (int k = 0; k < 32; ++k) {
      float4 av = *(const float4*)&As[k][ty * 4];
      float a[4] = {av.x, av.y, av.z, av.w};
#pragma unroll
      for (int j5 = 0; j5 < 5; j5++) {
        float4 bv = *(const float4*)&Bs[j5][k][tx * 4];
        float b[4] = {bv.x, bv.y, bv.z, bv.w};
#pragma unroll
        for (int i = 0; i < 4; i++)
#pragma unroll
          for (int j = 0; j < 4; j++) acc[j5][i][j] = fmaf(a[i], b[j], acc[j5][i][j]);
      }
    }
  }
#pragma unroll
  for (int i = 0; i < 4; i++) {
    int r = row0 + ty * 4 + i;
    *(float4*)&hpre[(size_t)r * D2 + tx * 4] =
        make_float4(acc[0][i][0], acc[0][i][1], acc[0][i][2], acc[0][i][3]);
#pragma unroll
    for (int j5 = 1; j5 < 5; j5++)
      *(float4*)&outp[(size_t)r * COUT + (j5 - 1) * 64 + tx * 4] =
          make_float4(acc[j5][i][0], acc[j5][i][1], acc[j5][i][2], acc[j5][i][3]);
  }
  // fused BN1 column stats over this block's 64 rows of hpre chunk (acc[0])
  __syncthreads();
#pragma unroll
  for (int j = 0; j < 4; j++)
    cs[ty][tx * 4 + j] = acc[0][0][j] + acc[0][1][j] + acc[0][2][j] + acc[0][3][j];
  __syncthreads();
  if (t < 64) {
    float s = 0.f;
#pragma unroll
    for (int w = 0; w < 16; w++) s += cs[w][t];
    atomicAdd(&ws[WS_BN1_SUM + t], s);
  }
  __syncthreads();
#pragma unroll
  for (int j = 0; j < 4; j++) {
    float q = 0.f;
#pragma unroll
    for (int i = 0; i < 4; i++) q = fmaf(acc[0][i][j], acc[0][i][j], q);
    cs[ty][tx * 4 + j] = q;
  }
  __syncthreads();
  if (t < 64) {
    float q = 0.f;
#pragma unroll
    for (int w = 0; w < 16; w++) q += cs[w][t];
    atomicAdd(&ws[WS_BN1_SQ + t], q);
  }
}

// ---------------- k2b: finalize BN1 scale/shift ----------------
__global__ void k2b_fin1(const float* __restrict__ g1, const float* __restrict__ b1,
                         float* __restrict__ ws) {
  int c = threadIdx.x;  // 64
  float m = ws[WS_BN1_SUM + c] * (1.f / NPTS);
  float v = ws[WS_BN1_SQ + c] * (1.f / NPTS) - m * m;
  float sc = g1[c] / sqrtf(v + BEPS);
  ws[WS_DERIV + D_S1 + c] = sc;
  ws[WS_DERIV + D_T1 + c] = b1[c] - m * sc;
}

// ---------------- k3a: filter active pairs; build pair list + point list ------
__global__ __launch_bounds__(256) void k3a_filter(const int* __restrict__ idx,
                                                  const float* __restrict__ pos,
                                                  const float* __restrict__ kpts,
                                                  float* __restrict__ ws, int cap) {
  __shared__ float kp[NKP * 3];
  int t = threadIdx.x;
  if (t < NKP * 3) kp[t] = kpts[t];
  __syncthreads();
  int id = blockIdx.x * 256 + t;
  int p = id >> 4;
  int ia = idx[id];
  if (ia >= NPTS) return;  // shadow neighbor
  float px = pos[p * 3 + 0], py = pos[p * 3 + 1], pz = pos[p * 3 + 2];
  float dx = pos[ia * 3 + 0] - px, dy = pos[ia * 3 + 1] - py, dz = pos[ia * 3 + 2] - pz;
  const float thr = PINF * PINF * 1.0001f;
  bool act = false;
#pragma unroll
  for (int k = 0; k < NKP; k++) {
    float ex = dx - kp[k * 3 + 0], ey = dy - kp[k * 3 + 1], ez = dz - kp[k * 3 + 2];
    float s = fmaf(ex, ex, fmaf(ey, ey, ez * ez));
    act = act || (s < thr);
  }
  if (act) {
    int slot = atomicAdd((int*)&ws[WS_PAIRCNT], 1);
    if (slot < cap) {
      int* pairs = (int*)&ws[WS_PAIRS];
      pairs[2 * slot] = p;
      pairs[2 * slot + 1] = ia;
    }
    int* flags = (int*)&ws[WS_FLAGS];
    if (atomicExch(&flags[p], 1) == 0) {
      int ps = atomicAdd((int*)&ws[WS_PTCNT], 1);
      ((int*)&ws[WS_PLIST])[ps] = p;
    }
  }
}

// ---------------- k3c: zero kppre rows of active points only ----------------
__global__ __launch_bounds__(256) void k3c_zero_active(float* __restrict__ ws) {
  const int l = threadIdx.x & 63;
  const int g = blockIdx.x * 4 + (threadIdx.x >> 6);
  const int nw = gridDim.x * 4;
  const int* plist = (const int*)&ws[WS_PLIST];
  int pcnt = ((const int*)ws)[WS_PTCNT];
  float* kppre = &ws[WS_KPPRE];
  for (int i = g; i < pcnt; i += nw) kppre[(size_t)plist[i] * D2 + l] = 0.f;
}

// ---------------- k3b: process active pairs (wave per pair, shfl broadcast) ---
__global__ __launch_bounds__(256) void k3b_active(const float* __restrict__ pos,
                                                  const float* __restrict__ kpts,
                                                  const float* __restrict__ kpw,
                                                  float* __restrict__ ws, int cap) {
  __shared__ float kp[NKP * 3];
  const int t = threadIdx.x;
  if (t < NKP * 3) kp[t] = kpts[t];
  __syncthreads();
  const int l = t & 63;
  const int g = blockIdx.x * 4 + (t >> 6);
  const int nw = gridDim.x * 4;
  const int* pairs = (const int*)&ws[WS_PAIRS];
  int npairs = ((const int*)ws)[WS_PAIRCNT];
  if (npairs > cap) npairs = cap;
  const float* hpre = &ws[WS_HPRE];
  const float s1l = ws[WS_DERIV + D_S1 + l];
  const float t1l = ws[WS_DERIV + D_T1 + l];
  float* kppre = &ws[WS_KPPRE];
  const float invp = 1.f / PINF;

  for (int i = g; i < npairs; i += nw) {
    int p = pairs[2 * i], ia = pairs[2 * i + 1];
    float px = pos[p * 3 + 0], py = pos[p * 3 + 1], pz = pos[p * 3 + 2];
    float dx = pos[ia * 3 + 0] - px, dy = pos[ia * 3 + 1] - py, dz = pos[ia * 3 + 2] - pz;
    float w[NKP];
#pragma unroll
    for (int k = 0; k < NKP; k++) {
      float ex = dx - kp[k * 3 + 0], ey = dy - kp[k * 3 + 1], ez = dz - kp[k * 3 + 2];
      float s = fmaf(ex, ex, fmaf(ey, ey, ez * ez));
      w[k] = fmaxf(0.f, 1.f - sqrtf(s) * invp);
    }
    float f = lrelu(fmaf(s1l, hpre[(size_t)ia * D2 + l], t1l));
    float accd = 0.f;
    bool any = false;
#pragma unroll
    for (int k = 0; k < NKP; k++) {
      if (w[k] > 0.f) {
        any = true;
        const float* kwk = kpw + ((size_t)k << 12) + l;
        float m0 = 0.f, m1 = 0.f, m2 = 0.f, m3 = 0.f;
#pragma unroll
        for (int c = 0; c < D2; c += 4) {
          float f0 = __shfl(f, c + 0), f1 = __shfl(f, c + 1);
          float f2 = __shfl(f, c + 2), f3 = __shfl(f, c + 3);
          m0 = fmaf(f0, kwk[(c + 0) * D2], m0);
          m1 = fmaf(f1, kwk[(c + 1) * D2], m1);
          m2 = fmaf(f2, kwk[(c + 2) * D2], m2);
          m3 = fmaf(f3, kwk[(c + 3) * D2], m3);
        }
        accd = fmaf(w[k], (m0 + m1) + (m2 + m3), accd);
      }
    }
    if (any) atomicAdd(&kppre[(size_t)p * D2 + l], accd);
  }
}

// ---------------- k4: BN_kp stats over active rows (zeros elsewhere) ----------
__global__ __launch_bounds__(256) void k4_stats_kp(float* __restrict__ ws) {
  const int t = threadIdx.x;
  const int l = t & 63, wv = t >> 6;
  const int g = blockIdx.x * 4 + wv;
  const int nw = gridDim.x * 4;
  const int* plist = (const int*)&ws[WS_PLIST];
  int pcnt = ((const int*)ws)[WS_PTCNT];
  const float* kppre = &ws[WS_KPPRE];
  float s = 0.f, q = 0.f;
  for (int i = g; i < pcnt; i += nw) {
    float v = kppre[(size_t)plist[i] * D2 + l];
    s += v;
    q = fmaf(v, v, q);
  }
  __shared__ float red[4][64];
  red[wv][l] = s;
  __syncthreads();
  if (t < 64) atomicAdd(&ws[WS_KP_SUM + t], red[0][t] + red[1][t] + red[2][t] + red[3][t]);
  __syncthreads();
  red[wv][l] = q;
  __syncthreads();
  if (t < 64) atomicAdd(&ws[WS_KP_SQ + t], red[0][t] + red[1][t] + red[2][t] + red[3][t]);
}

// ---------------- k4b: finalize BN_kp; base z row; base u2 row ----------------
__global__ void k4b_fin_kp(const float* __restrict__ gkp, const float* __restrict__ bkp,
                           const float* __restrict__ W2, float* __restrict__ ws) {
  int t = threadIdx.x;  // 256
  __shared__ float zb[64];
  if (t < 64) {
    float m = ws[WS_KP_SUM + t] * (1.f / NPTS);
    float v = ws[WS_KP_SQ + t] * (1.f / NPTS) - m * m;
    float sc = gkp[t] / sqrtf(v + BEPS);
    float sh = bkp[t] - m * sc;
    ws[WS_DERIV + D_SKP + t] = sc;
    ws[WS_DERIV + D_TKP + t] = sh;
    float z = lrelu(sh);
    ws[WS_DERIV + D_ZB + t] = z;
    zb[t] = z;
  }
  __syncthreads();
  float u = 0.f;
  for (int c = 0; c < D2; c++) u = fmaf(zb[c], W2[(size_t)c * COUT + t], u);
  ws[WS_DERIV + D_BU2 + t] = u;
}

// ---------------- k5: BN2 stats centered on base row (wave per active point) --
__global__ __launch_bounds__(256) void k5_stats_u2(const float* __restrict__ W2,
                                                   float* __restrict__ ws) {
  const int t = threadIdx.x;
  const int l = t & 63, wv = t >> 6;
  const int g = blockIdx.x * 4 + wv;
  const int nw = gridDim.x * 4;
  const int* plist = (const int*)&ws[WS_PLIST];
  int pcnt = ((const int*)ws)[WS_PTCNT];
  const float* kppre = &ws[WS_KPPRE];
  const float skl = ws[WS_DERIV + D_SKP + l];
  const float tkl = ws[WS_DERIV + D_TKP + l];
  float bu[4], ds[4] = {0.f, 0.f, 0.f, 0.f}, dq[4] = {0.f, 0.f, 0.f, 0.f};
#pragma unroll
  for (int j = 0; j < 4; j++) bu[j] = ws[WS_DERIV + D_BU2 + j * 64 + l];

  for (int i = g; i < pcnt; i += nw) {
    int p = plist[i];
    float z = lrelu(fmaf(skl, kppre[(size_t)p * D2 + l], tkl));
    float u0 = 0.f, u1 = 0.f, u2 = 0.f, u3 = 0.f;
#pragma unroll
    for (int c = 0; c < D2; c++) {
      float zc = __shfl(z, c);
      const float* w2c = &W2[(size_t)c * COUT + l];
      u0 = fmaf(zc, w2c[0], u0);
      u1 = fmaf(zc, w2c[64], u1);
      u2 = fmaf(zc, w2c[128], u2);
      u3 = fmaf(zc, w2c[192], u3);
    }
    float du0 = u0 - bu[0], du1 = u1 - bu[1], du2 = u2 - bu[2], du3 = u3 - bu[3];
    ds[0] += du0; ds[1] += du1; ds[2] += du2; ds[3] += du3;
    dq[0] = fmaf(du0, du0, dq[0]); dq[1] = fmaf(du1, du1, dq[1]);
    dq[2] = fmaf(du2, du2, dq[2]); dq[3] = fmaf(du3, du3, dq[3]);
  }
  __shared__ float red[4][256];
#pragma unroll
  for (int j = 0; j < 4; j++) red[wv][j * 64 + l] = ds[j];
  __syncthreads();
  atomicAdd(&ws[WS_U2_DSUM + t], red[0][t] + red[1][t] + red[2][t] + red[3][t]);
  __syncthreads();
#pragma unroll
  for (int j = 0; j < 4; j++) red[wv][j * 64 + l] = dq[j];
  __syncthreads();
  atomicAdd(&ws[WS_U2_DSQ + t], red[0][t] + red[1][t] + red[2][t] + red[3][t]);
}

// ---------------- k6: finalize BN2; final base output row ----------------
__global__ void k6_fin2(const float* __restrict__ g2, const float* __restrict__ b2,
                        float* __restrict__ ws) {
  int t = threadIdx.x;  // 256
  float bu = ws[WS_DERIV + D_BU2 + t];
  float dm = ws[WS_U2_DSUM + t] * (1.f / NPTS);
  float dv = ws[WS_U2_DSQ + t] * (1.f / NPTS) - dm * dm;
  float mean = bu + dm;
  float sc = g2[t] / sqrtf(dv + BEPS);
  float sh = b2[t] - mean * sc;
  ws[WS_DERIV + D_S2 + t] = sc;
  ws[WS_DERIV + D_T2 + t] = sh;
  ws[WS_DERIV + D_FB + t] = lrelu(fmaf(sc, bu, sh));
}

// ---------------- k7i: inactive rows  out += final_base (wave-per-row skip) ---
__global__ __launch_bounds__(256) void k7i_inactive(float* __restrict__ out,
                                                    const float* __restrict__ ws) {
  const int* flags = (const int*)&ws[WS_FLAGS];
  const float* fb = &ws[WS_DERIV + D_FB];
  size_t n = (size_t)NPTS * 64;  // float4 units
  size_t stride = (size_t)gridDim.x * blockDim.x;
  for (size_t u = (size_t)blockIdx.x * blockDim.x + threadIdx.x; u < n; u += stride) {
    int r = (int)(u >> 6);
    if (flags[r]) continue;  // uniform across the wave (64 consecutive u share r)
    int s = (int)(u & 63);
    float4 o = ((float4*)out)[u];
    float4 f4 = *(const float4*)&fb[s * 4];
    o.x += f4.x; o.y += f4.y; o.z += f4.z; o.w += f4.w;
    ((float4*)out)[u] = o;
  }
}

// ---------------- k7a: active rows  out += lrelu(bn2(u2)) ----------------
__global__ __launch_bounds__(256) void k7a_active(const float* __restrict__ W2,
                                                  float* __restrict__ out,
                                                  float* __restrict__ ws) {
  const int t = threadIdx.x;
  const int l = t & 63;
  const int g = blockIdx.x * 4 + (t >> 6);
  const int nw = gridDim.x * 4;
  const int* plist = (const int*)&ws[WS_PLIST];
  int pcnt = ((const int*)ws)[WS_PTCNT];
  const float* kppre = &ws[WS_KPPRE];
  const float skl = ws[WS_DERIV + D_SKP + l];
  const float tkl = ws[WS_DERIV + D_TKP + l];
  float s2[4], t2[4];
#pragma unroll
  for (int j = 0; j < 4; j++) {
    s2[j] = ws[WS_DERIV + D_S2 + j * 64 + l];
    t2[j] = ws[WS_DERIV + D_T2 + j * 64 + l];
  }
  for (int i = g; i < pcnt; i += nw) {
    int p = plist[i];
    float z = lrelu(fmaf(skl, kppre[(size_t)p * D2 + l], tkl));
    float u0 = 0.f, u1 = 0.f, u2 = 0.f, u3 = 0.f;
#pragma unroll
    for (int c = 0; c < D2; c++) {
      float zc = __shfl(z, c);
      const float* w2c = &W2[(size_t)c * COUT + l];
      u0 = fmaf(zc, w2c[0], u0);
      u1 = fmaf(zc, w2c[64], u1);
      u2 = fmaf(zc, w2c[128], u2);
      u3 = fmaf(zc, w2c[192], u3);
    }
    float* op = &out[(size_t)p * COUT + l];
    op[0]   += lrelu(fmaf(s2[0], u0, t2[0]));
    op[64]  += lrelu(fmaf(s2[1], u1, t2[1]));
    op[128] += lrelu(fmaf(s2[2], u2, t2[2]));
    op[192] += lrelu(fmaf(s2[3], u3, t2[3]));
  }
}

// ---------------- launch ----------------
extern "C" void kernel_launch(void* const* d_in, const int* in_sizes, int n_in,
                              void* d_out, int out_size, void* d_ws, size_t ws_size,
                              hipStream_t stream) {
  const float* x    = (const float*)d_in[0];
  const float* pos  = (const float*)d_in[1];
  const int*   idx  = (const int*)d_in[2];
  const float* W1   = (const float*)d_in[3];
  const float* g1   = (const float*)d_in[4];
  const float* b1   = (const float*)d_in[5];
  const float* kpts = (const float*)d_in[6];
  const float* kpw  = (const float*)d_in[7];
  const float* gkp  = (const float*)d_in[8];
  const float* bkp  = (const float*)d_in[9];
  const float* W2   = (const float*)d_in[10];
  const float* g2   = (const float*)d_in[11];
  const float* b2   = (const float*)d_in[12];
  const float* Wsc  = (const float*)d_in[13];
  float* out = (float*)d_out;
  float* ws = (float*)d_ws;

  long long cap_ll = ((long long)(ws_size / 4) - (long long)WS_PAIRS) / 2;
  if (cap_ll < 0) cap_ll = 0;
  if (cap_ll > (long long)NPTS * NNB) cap_ll = (long long)NPTS * NNB;
  int cap = (int)cap_ll;

  k0_zero<<<256, 256, 0, stream>>>(ws);
  k1_gemm<<<NPTS / 64, 256, 0, stream>>>(x, W1, Wsc, &ws[WS_HPRE], out, ws);
  k2b_fin1<<<1, 64, 0, stream>>>(g1, b1, ws);
  k3a_filter<<<NPTS * NNB / 256, 256, 0, stream>>>(idx, pos, kpts, ws, cap);
  k3c_zero_active<<<256, 256, 0, stream>>>(ws);
  k3b_active<<<2048, 256, 0, stream>>>(pos, kpts, kpw, ws, cap);
  k4_stats_kp<<<256, 256, 0, stream>>>(ws);
  k4b_fin_kp<<<1, 256, 0, stream>>>(gkp, bkp, W2, ws);
  k5_stats_u2<<<512, 256, 0, stream>>>(W2, ws);
  k6_fin2<<<1, 256, 0, stream>>>(g2, b2, ws);
  k7i_inactive<<<2048, 256, 0, stream>>>(out, ws);
  k7a_active<<<512, 256, 0, stream>>>(W2, out, ws);
}

// Round 5
// 1064.636 us; speedup vs baseline: 1.9106x; 1.9106x over previous
//
#include <hip/hip_runtime.h>
#include <cstdint>
#include <cstddef>

#define NPTS   262144
#define NNB    16
#define NKP    15
#define CIN    128
#define D2     64
#define COUT   256
#define PINF   0.04f
#define NSLOPE 0.2f
#define BEPS   1e-5f

// ---------------- workspace layout (float element offsets) ----------------
#define WS_BN1_SUM  0            // 64
#define WS_BN1_SQ   64           // 64
#define WS_KP_SUM   128          // 64
#define WS_KP_SQ    192          // 64
#define WS_U2_DSUM  256          // 256
#define WS_U2_DSQ   512          // 256
#define WS_PAIRCNT  768          // 1 int
#define WS_PTCNT    769          // 1 int
#define WS_FLAGS    1024         // NPTS ints
#define WS_PLIST    (1024 + NPTS)                      // NPTS ints (active point ids)
#define WS_ZERO_END WS_PLIST                           // zero [0, WS_PLIST)
#define WS_HPRE     (WS_PLIST + NPTS)                  // NPTS*64 floats
#define WS_KPPRE    (WS_HPRE + (size_t)NPTS * D2)      // NPTS*64 floats (active rows zeroed by k3c)
#define WS_DERIV    (WS_KPPRE + (size_t)NPTS * D2)     // 2048 floats
#define D_S1   0
#define D_T1   64
#define D_SKP  128
#define D_TKP  192
#define D_ZB   256
#define D_S2   320
#define D_T2   576
#define D_BU2  832
#define D_FB   1088
#define WS_PAIRS    (WS_DERIV + 2048)                  // int2 per pair

__device__ __forceinline__ float lrelu(float v) { return v >= 0.f ? v : NSLOPE * v; }

// ---------------- k0: zero stats/counters/flags (~1 MB) ----------------
__global__ void k0_zero(float* __restrict__ ws) {
  size_t n4 = WS_ZERO_END / 4;
  float4 z = make_float4(0.f, 0.f, 0.f, 0.f);
  for (size_t i = (size_t)blockIdx.x * blockDim.x + threadIdx.x; i < n4;
       i += (size_t)gridDim.x * blockDim.x)
    ((float4*)ws)[i] = z;
}

// ---------------- k1: fused GEMM  [h_pre | sc] = x @ [W1 | Wsc], + BN1 stats --
__global__ __launch_bounds__(256) void k1_gemm(const float* __restrict__ x,
                                               const float* __restrict__ W1,
                                               const float* __restrict__ Wsc,
                                               float* __restrict__ hpre,
                                               float* __restrict__ outp,
                                               float* __restrict__ ws) {
  __shared__ __align__(16) float As[32][72];
  __shared__ __align__(16) float Bs[5][32][64];
  __shared__ float cs[16][68];
  const int t = threadIdx.x;
  const int row0 = blockIdx.x * 64;
  const int tx = t & 15, ty = t >> 4;
  float acc[5][4][4];
#pragma unroll
  for (int j5 = 0; j5 < 5; j5++)
#pragma unroll
    for (int i = 0; i < 4; i++)
#pragma unroll
      for (int j = 0; j < 4; j++) acc[j5][i][j] = 0.f;

  for (int k0 = 0; k0 < CIN; k0 += 32) {
    __syncthreads();
    {
      int r = t >> 2;
      int c = (t & 3) * 8;
      const float* src = &x[(size_t)(row0 + r) * CIN + k0 + c];
      float4 a0 = *(const float4*)src;
      float4 a1 = *(const float4*)(src + 4);
      As[c + 0][r] = a0.x; As[c + 1][r] = a0.y; As[c + 2][r] = a0.z; As[c + 3][r] = a0.w;
      As[c + 4][r] = a1.x; As[c + 5][r] = a1.y; As[c + 6][r] = a1.z; As[c + 7][r] = a1.w;
    }
    {
      int kk = t >> 3;
      int c = (t & 7) * 8;
#pragma unroll
      for (int j5 = 0; j5 < 5; j5++) {
        const float* B = (j5 == 0) ? &W1[(size_t)(k0 + kk) * D2 + c]
                                   : &Wsc[(size_t)(k0 + kk) * COUT + (j5 - 1) * 64 + c];
        float4 b0 = *(const float4*)B;
        float4 b1 = *(const float4*)(B + 4);
        *(float4*)&Bs[j5][kk][c] = b0;
        *(float4*)&Bs[j5][kk][c + 4] = b1;
      }
    }
    __syncthreads();
#pragma unroll
    for (int k = 0; k < 32; ++k) {
      float4 av = *(const float4*)&As[k][ty * 4];
      float a[4] = {av.x, av.y, av.z, av.w};
#pragma unroll
      for (int j5 = 0; j5 < 5; j5++) {
        float4 bv = *(const float4*)&Bs[j5][k][tx * 4];
        float b[4] = {bv.x, bv.y, bv.z, bv.w};
#pragma unroll
        for (int i = 0; i < 4; i++)
#pragma unroll
          for (int j = 0; j < 4; j++) acc[j5][i][j] = fmaf(a[i], b[j], acc[j5][i][j]);
      }
    }
  }
#pragma unroll
  for (int i = 0; i < 4; i++) {
    int r = row0 + ty * 4 + i;
    *(float4*)&hpre[(size_t)r * D2 + tx * 4] =
        make_float4(acc[0][i][0], acc[0][i][1], acc[0][i][2], acc[0][i][3]);
#pragma unroll
    for (int j5 = 1; j5 < 5; j5++)
      *(float4*)&outp[(size_t)r * COUT + (j5 - 1) * 64 + tx * 4] =
          make_float4(acc[j5][i][0], acc[j5][i][1], acc[j5][i][2], acc[j5][i][3]);
  }
  // fused BN1 column stats over this block's 64 rows of hpre chunk (acc[0])
  __syncthreads();
#pragma unroll
  for (int j = 0; j < 4; j++)
    cs[ty][tx * 4 + j] = acc[0][0][j] + acc[0][1][j] + acc[0][2][j] + acc[0][3][j];
  __syncthreads();
  if (t < 64) {
    float s = 0.f;
#pragma unroll
    for (int w = 0; w < 16; w++) s += cs[w][t];
    atomicAdd(&ws[WS_BN1_SUM + t], s);
  }
  __syncthreads();
#pragma unroll
  for (int j = 0; j < 4; j++) {
    float q = 0.f;
#pragma unroll
    for (int i = 0; i < 4; i++) q = fmaf(acc[0][i][j], acc[0][i][j], q);
    cs[ty][tx * 4 + j] = q;
  }
  __syncthreads();
  if (t < 64) {
    float q = 0.f;
#pragma unroll
    for (int w = 0; w < 16; w++) q += cs[w][t];
    atomicAdd(&ws[WS_BN1_SQ + t], q);
  }
}

// ---------------- k2b: finalize BN1 scale/shift ----------------
__global__ void k2b_fin1(const float* __restrict__ g1, const float* __restrict__ b1,
                         float* __restrict__ ws) {
  int c = threadIdx.x;  // 64
  float m = ws[WS_BN1_SUM + c] * (1.f / NPTS);
  float v = ws[WS_BN1_SQ + c] * (1.f / NPTS) - m * m;
  float sc = g1[c] / sqrtf(v + BEPS);
  ws[WS_DERIV + D_S1 + c] = sc;
  ws[WS_DERIV + D_T1 + c] = b1[c] - m * sc;
}

// ---------------- k3a: filter active pairs; build pair list + point list ------
__global__ __launch_bounds__(256) void k3a_filter(const int* __restrict__ idx,
                                                  const float* __restrict__ pos,
                                                  const float* __restrict__ kpts,
                                                  float* __restrict__ ws, int cap) {
  __shared__ float kp[NKP * 3];
  int t = threadIdx.x;
  if (t < NKP * 3) kp[t] = kpts[t];
  __syncthreads();
  int id = blockIdx.x * 256 + t;
  int p = id >> 4;
  int ia = idx[id];
  if (ia >= NPTS) return;  // shadow neighbor
  float px = pos[p * 3 + 0], py = pos[p * 3 + 1], pz = pos[p * 3 + 2];
  float dx = pos[ia * 3 + 0] - px, dy = pos[ia * 3 + 1] - py, dz = pos[ia * 3 + 2] - pz;
  const float thr = PINF * PINF * 1.0001f;
  bool act = false;
#pragma unroll 1
  for (int k = 0; k < NKP; k++) {
    float ex = dx - kp[k * 3 + 0], ey = dy - kp[k * 3 + 1], ez = dz - kp[k * 3 + 2];
    float s = fmaf(ex, ex, fmaf(ey, ey, ez * ez));
    act = act || (s < thr);
  }
  if (act) {
    int slot = atomicAdd((int*)&ws[WS_PAIRCNT], 1);
    if (slot < cap) {
      int* pairs = (int*)&ws[WS_PAIRS];
      pairs[2 * slot] = p;
      pairs[2 * slot + 1] = ia;
    }
    int* flags = (int*)&ws[WS_FLAGS];
    if (atomicExch(&flags[p], 1) == 0) {
      int ps = atomicAdd((int*)&ws[WS_PTCNT], 1);
      ((int*)&ws[WS_PLIST])[ps] = p;
    }
  }
}

// ---------------- k3c: zero kppre rows of active points only ----------------
__global__ __launch_bounds__(256) void k3c_zero_active(float* __restrict__ ws) {
  const int l = threadIdx.x & 63;
  const int g = blockIdx.x * 4 + (threadIdx.x >> 6);
  const int nw = gridDim.x * 4;
  const int* plist = (const int*)&ws[WS_PLIST];
  int pcnt = ((const int*)ws)[WS_PTCNT];
  float* kppre = &ws[WS_KPPRE];
  for (int i = g; i < pcnt; i += nw) kppre[(size_t)plist[i] * D2 + l] = 0.f;
}

// ---------------- k3b: process active pairs ----------------
// Register-light rewrite: wave-uniform active-k bitmask, #pragma unroll 1
// k-loop (defeats the 15x unroll that spilled ~6 KB/thread of scratch in
// rounds 1/3), pointer-bump inner matvec with 4 accumulators.
__global__ __launch_bounds__(256) void k3b_active(const float* __restrict__ pos,
                                                  const float* __restrict__ kpts,
                                                  const float* __restrict__ kpw,
                                                  float* __restrict__ ws, int cap) {
  __shared__ float kp[NKP * 3];
  const int t = threadIdx.x;
  if (t < NKP * 3) kp[t] = kpts[t];
  __syncthreads();
  const int l = t & 63;
  const int g = blockIdx.x * 4 + (t >> 6);
  const int nw = gridDim.x * 4;
  const int* pairs = (const int*)&ws[WS_PAIRS];
  int npairs = ((const int*)ws)[WS_PAIRCNT];
  if (npairs > cap) npairs = cap;
  const float* hpre = &ws[WS_HPRE];
  const float s1l = ws[WS_DERIV + D_S1 + l];
  const float t1l = ws[WS_DERIV + D_T1 + l];
  float* kppre = &ws[WS_KPPRE];
  const float invp = 1.f / PINF;
  const float r2 = PINF * PINF;

#pragma unroll 1
  for (int i = g; i < npairs; i += nw) {
    int p = pairs[2 * i], ia = pairs[2 * i + 1];
    float px = pos[p * 3 + 0], py = pos[p * 3 + 1], pz = pos[p * 3 + 2];
    float dx = pos[ia * 3 + 0] - px, dy = pos[ia * 3 + 1] - py, dz = pos[ia * 3 + 2] - pz;
    // wave-uniform mask of active kernel points (identical on all 64 lanes)
    unsigned mask = 0;
#pragma unroll 1
    for (int k = 0; k < NKP; k++) {
      float ex = dx - kp[k * 3 + 0], ey = dy - kp[k * 3 + 1], ez = dz - kp[k * 3 + 2];
      float s = fmaf(ex, ex, fmaf(ey, ey, ez * ez));
      if (s < r2) mask |= (1u << k);
    }
    if (mask == 0) continue;  // filter-inflation marginal: exact-zero contribution
    float f = lrelu(fmaf(s1l, hpre[(size_t)ia * D2 + l], t1l));
    float accd = 0.f;
#pragma unroll 1
    while (mask) {
      int k = __ffs(mask) - 1;
      mask &= mask - 1;
      float ex = dx - kp[k * 3 + 0], ey = dy - kp[k * 3 + 1], ez = dz - kp[k * 3 + 2];
      float s = fmaf(ex, ex, fmaf(ey, ey, ez * ez));
      float wk = 1.f - sqrtf(s) * invp;  // > 0 by mask construction
      const float* kwk = kpw + ((size_t)k << 12) + l;
      float m0 = 0.f, m1 = 0.f, m2 = 0.f, m3 = 0.f;
#pragma unroll 1
      for (int c = 0; c < D2; c += 4) {
        float f0 = __shfl(f, c + 0), f1 = __shfl(f, c + 1);
        float f2 = __shfl(f, c + 2), f3 = __shfl(f, c + 3);
        m0 = fmaf(f0, kwk[0], m0);
        m1 = fmaf(f1, kwk[64], m1);
        m2 = fmaf(f2, kwk[128], m2);
        m3 = fmaf(f3, kwk[192], m3);
        kwk += 256;
      }
      accd = fmaf(wk, (m0 + m1) + (m2 + m3), accd);
    }
    atomicAdd(&kppre[(size_t)p * D2 + l], accd);
  }
}

// ---------------- k4: BN_kp stats over active rows (zeros elsewhere) ----------
__global__ __launch_bounds__(256) void k4_stats_kp(float* __restrict__ ws) {
  const int t = threadIdx.x;
  const int l = t & 63, wv = t >> 6;
  const int g = blockIdx.x * 4 + wv;
  const int nw = gridDim.x * 4;
  const int* plist = (const int*)&ws[WS_PLIST];
  int pcnt = ((const int*)ws)[WS_PTCNT];
  const float* kppre = &ws[WS_KPPRE];
  float s = 0.f, q = 0.f;
  for (int i = g; i < pcnt; i += nw) {
    float v = kppre[(size_t)plist[i] * D2 + l];
    s += v;
    q = fmaf(v, v, q);
  }
  __shared__ float red[4][64];
  red[wv][l] = s;
  __syncthreads();
  if (t < 64) atomicAdd(&ws[WS_KP_SUM + t], red[0][t] + red[1][t] + red[2][t] + red[3][t]);
  __syncthreads();
  red[wv][l] = q;
  __syncthreads();
  if (t < 64) atomicAdd(&ws[WS_KP_SQ + t], red[0][t] + red[1][t] + red[2][t] + red[3][t]);
}

// ---------------- k4b: finalize BN_kp; base z row; base u2 row ----------------
__global__ void k4b_fin_kp(const float* __restrict__ gkp, const float* __restrict__ bkp,
                           const float* __restrict__ W2, float* __restrict__ ws) {
  int t = threadIdx.x;  // 256
  __shared__ float zb[64];
  if (t < 64) {
    float m = ws[WS_KP_SUM + t] * (1.f / NPTS);
    float v = ws[WS_KP_SQ + t] * (1.f / NPTS) - m * m;
    float sc = gkp[t] / sqrtf(v + BEPS);
    float sh = bkp[t] - m * sc;
    ws[WS_DERIV + D_SKP + t] = sc;
    ws[WS_DERIV + D_TKP + t] = sh;
    float z = lrelu(sh);
    ws[WS_DERIV + D_ZB + t] = z;
    zb[t] = z;
  }
  __syncthreads();
  float u = 0.f;
  for (int c = 0; c < D2; c++) u = fmaf(zb[c], W2[(size_t)c * COUT + t], u);
  ws[WS_DERIV + D_BU2 + t] = u;
}

// ---------------- k5: BN2 stats centered on base row (wave per active point) --
__global__ __launch_bounds__(256) void k5_stats_u2(const float* __restrict__ W2,
                                                   float* __restrict__ ws) {
  const int t = threadIdx.x;
  const int l = t & 63, wv = t >> 6;
  const int g = blockIdx.x * 4 + wv;
  const int nw = gridDim.x * 4;
  const int* plist = (const int*)&ws[WS_PLIST];
  int pcnt = ((const int*)ws)[WS_PTCNT];
  const float* kppre = &ws[WS_KPPRE];
  const float skl = ws[WS_DERIV + D_SKP + l];
  const float tkl = ws[WS_DERIV + D_TKP + l];
  float bu[4], ds[4] = {0.f, 0.f, 0.f, 0.f}, dq[4] = {0.f, 0.f, 0.f, 0.f};
#pragma unroll
  for (int j = 0; j < 4; j++) bu[j] = ws[WS_DERIV + D_BU2 + j * 64 + l];

  for (int i = g; i < pcnt; i += nw) {
    int p = plist[i];
    float z = lrelu(fmaf(skl, kppre[(size_t)p * D2 + l], tkl));
    float u0 = 0.f, u1 = 0.f, u2 = 0.f, u3 = 0.f;
#pragma unroll
    for (int c = 0; c < D2; c++) {
      float zc = __shfl(z, c);
      const float* w2c = &W2[(size_t)c * COUT + l];
      u0 = fmaf(zc, w2c[0], u0);
      u1 = fmaf(zc, w2c[64], u1);
      u2 = fmaf(zc, w2c[128], u2);
      u3 = fmaf(zc, w2c[192], u3);
    }
    float du0 = u0 - bu[0], du1 = u1 - bu[1], du2 = u2 - bu[2], du3 = u3 - bu[3];
    ds[0] += du0; ds[1] += du1; ds[2] += du2; ds[3] += du3;
    dq[0] = fmaf(du0, du0, dq[0]); dq[1] = fmaf(du1, du1, dq[1]);
    dq[2] = fmaf(du2, du2, dq[2]); dq[3] = fmaf(du3, du3, dq[3]);
  }
  __shared__ float red[4][256];
#pragma unroll
  for (int j = 0; j < 4; j++) red[wv][j * 64 + l] = ds[j];
  __syncthreads();
  atomicAdd(&ws[WS_U2_DSUM + t], red[0][t] + red[1][t] + red[2][t] + red[3][t]);
  __syncthreads();
#pragma unroll
  for (int j = 0; j < 4; j++) red[wv][j * 64 + l] = dq[j];
  __syncthreads();
  atomicAdd(&ws[WS_U2_DSQ + t], red[0][t] + red[1][t] + red[2][t] + red[3][t]);
}

// ---------------- k6: finalize BN2; final base output row ----------------
__global__ void k6_fin2(const float* __restrict__ g2, const float* __restrict__ b2,
                        float* __restrict__ ws) {
  int t = threadIdx.x;  // 256
  float bu = ws[WS_DERIV + D_BU2 + t];
  float dm = ws[WS_U2_DSUM + t] * (1.f / NPTS);
  float dv = ws[WS_U2_DSQ + t] * (1.f / NPTS) - dm * dm;
  float mean = bu + dm;
  float sc = g2[t] / sqrtf(dv + BEPS);
  float sh = b2[t] - mean * sc;
  ws[WS_DERIV + D_S2 + t] = sc;
  ws[WS_DERIV + D_T2 + t] = sh;
  ws[WS_DERIV + D_FB + t] = lrelu(fmaf(sc, bu, sh));
}

// ---------------- k7i: inactive rows  out += final_base (wave-per-row skip) ---
__global__ __launch_bounds__(256) void k7i_inactive(float* __restrict__ out,
                                                    const float* __restrict__ ws) {
  const int* flags = (const int*)&ws[WS_FLAGS];
  const float* fb = &ws[WS_DERIV + D_FB];
  size_t n = (size_t)NPTS * 64;  // float4 units
  size_t stride = (size_t)gridDim.x * blockDim.x;
  for (size_t u = (size_t)blockIdx.x * blockDim.x + threadIdx.x; u < n; u += stride) {
    int r = (int)(u >> 6);
    if (flags[r]) continue;  // uniform across the wave (64 consecutive u share r)
    int s = (int)(u & 63);
    float4 o = ((float4*)out)[u];
    float4 f4 = *(const float4*)&fb[s * 4];
    o.x += f4.x; o.y += f4.y; o.z += f4.z; o.w += f4.w;
    ((float4*)out)[u] = o;
  }
}

// ---------------- k7a: active rows  out += lrelu(bn2(u2)) ----------------
__global__ __launch_bounds__(256) void k7a_active(const float* __restrict__ W2,
                                                  float* __restrict__ out,
                                                  float* __restrict__ ws) {
  const int t = threadIdx.x;
  const int l = t & 63;
  const int g = blockIdx.x * 4 + (t >> 6);
  const int nw = gridDim.x * 4;
  const int* plist = (const int*)&ws[WS_PLIST];
  int pcnt = ((const int*)ws)[WS_PTCNT];
  const float* kppre = &ws[WS_KPPRE];
  const float skl = ws[WS_DERIV + D_SKP + l];
  const float tkl = ws[WS_DERIV + D_TKP + l];
  float s2[4], t2[4];
#pragma unroll
  for (int j = 0; j < 4; j++) {
    s2[j] = ws[WS_DERIV + D_S2 + j * 64 + l];
    t2[j] = ws[WS_DERIV + D_T2 + j * 64 + l];
  }
  for (int i = g; i < pcnt; i += nw) {
    int p = plist[i];
    float z = lrelu(fmaf(skl, kppre[(size_t)p * D2 + l], tkl));
    float u0 = 0.f, u1 = 0.f, u2 = 0.f, u3 = 0.f;
#pragma unroll
    for (int c = 0; c < D2; c++) {
      float zc = __shfl(z, c);
      const float* w2c = &W2[(size_t)c * COUT + l];
      u0 = fmaf(zc, w2c[0], u0);
      u1 = fmaf(zc, w2c[64], u1);
      u2 = fmaf(zc, w2c[128], u2);
      u3 = fmaf(zc, w2c[192], u3);
    }
    float* op = &out[(size_t)p * COUT + l];
    op[0]   += lrelu(fmaf(s2[0], u0, t2[0]));
    op[64]  += lrelu(fmaf(s2[1], u1, t2[1]));
    op[128] += lrelu(fmaf(s2[2], u2, t2[2]));
    op[192] += lrelu(fmaf(s2[3], u3, t2[3]));
  }
}

// ---------------- launch ----------------
extern "C" void kernel_launch(void* const* d_in, const int* in_sizes, int n_in,
                              void* d_out, int out_size, void* d_ws, size_t ws_size,
                              hipStream_t stream) {
  const float* x    = (const float*)d_in[0];
  const float* pos  = (const float*)d_in[1];
  const int*   idx  = (const int*)d_in[2];
  const float* W1   = (const float*)d_in[3];
  const float* g1   = (const float*)d_in[4];
  const float* b1   = (const float*)d_in[5];
  const float* kpts = (const float*)d_in[6];
  const float* kpw  = (const float*)d_in[7];
  const float* gkp  = (const float*)d_in[8];
  const float* bkp  = (const float*)d_in[9];
  const float* W2   = (const float*)d_in[10];
  const float* g2   = (const float*)d_in[11];
  const float* b2   = (const float*)d_in[12];
  const float* Wsc  = (const float*)d_in[13];
  float* out = (float*)d_out;
  float* ws = (float*)d_ws;

  long long cap_ll = ((long long)(ws_size / 4) - (long long)WS_PAIRS) / 2;
  if (cap_ll < 0) cap_ll = 0;
  if (cap_ll > (long long)NPTS * NNB) cap_ll = (long long)NPTS * NNB;
  int cap = (int)cap_ll;

  k0_zero<<<256, 256, 0, stream>>>(ws);
  k1_gemm<<<NPTS / 64, 256, 0, stream>>>(x, W1, Wsc, &ws[WS_HPRE], out, ws);
  k2b_fin1<<<1, 64, 0, stream>>>(g1, b1, ws);
  k3a_filter<<<NPTS * NNB / 256, 256, 0, stream>>>(idx, pos, kpts, ws, cap);
  k3c_zero_active<<<256, 256, 0, stream>>>(ws);
  k3b_active<<<512, 256, 0, stream>>>(pos, kpts, kpw, ws, cap);
  k4_stats_kp<<<256, 256, 0, stream>>>(ws);
  k4b_fin_kp<<<1, 256, 0, stream>>>(gkp, bkp, W2, ws);
  k5_stats_u2<<<512, 256, 0, stream>>>(W2, ws);
  k6_fin2<<<1, 256, 0, stream>>>(g2, b2, ws);
  k7i_inactive<<<2048, 256, 0, stream>>>(out, ws);
  k7a_active<<<512, 256, 0, stream>>>(W2, out, ws);
}

// Round 6
// 1036.167 us; speedup vs baseline: 1.9631x; 1.0275x over previous
//
#include <hip/hip_runtime.h>
#include <cstdint>
#include <cstddef>

#define NPTS   262144
#define NNB    16
#define NKP    15
#define CIN    128
#define D2     64
#define COUT   256
#define PINF   0.04f
#define NSLOPE 0.2f
#define BEPS   1e-5f

// ---------------- workspace layout (float element offsets) ----------------
#define WS_BN1_SUM  0            // 64
#define WS_BN1_SQ   64           // 64
#define WS_KP_SUM   128          // 64
#define WS_KP_SQ    192          // 64
#define WS_U2_DSUM  256          // 256
#define WS_U2_DSQ   512          // 256
#define WS_PAIRCNT  768          // 1 int
#define WS_PTCNT    769          // 1 int
#define WS_FLAGS    1024         // NPTS ints
#define WS_PLIST    (1024 + NPTS)                      // NPTS ints (active point ids)
#define WS_ZERO_END WS_PLIST                           // zero [0, WS_PLIST)
#define WS_HPRE     (WS_PLIST + NPTS)                  // NPTS*64 floats
#define WS_KPPRE    (WS_HPRE + (size_t)NPTS * D2)      // NPTS*64 floats (active rows zeroed in k3a)
#define WS_DERIV    (WS_KPPRE + (size_t)NPTS * D2)     // 2048 floats
#define D_S1   0
#define D_T1   64
#define D_SKP  128
#define D_TKP  192
#define D_ZB   256
#define D_S2   320
#define D_T2   576
#define D_BU2  832
#define D_FB   1088
#define WS_PAIRS    (WS_DERIV + 2048)                  // int2 per pair

__device__ __forceinline__ float lrelu(float v) { return v >= 0.f ? v : NSLOPE * v; }

// ---------------- k0: zero stats/counters/flags (~1 MB) ----------------
__global__ void k0_zero(float* __restrict__ ws) {
  size_t n4 = WS_ZERO_END / 4;
  float4 z = make_float4(0.f, 0.f, 0.f, 0.f);
  for (size_t i = (size_t)blockIdx.x * blockDim.x + threadIdx.x; i < n4;
       i += (size_t)gridDim.x * blockDim.x)
    ((float4*)ws)[i] = z;
}

// ---------------- k1a: hpre = x @ W1  (+ fused BN1 column stats) ----------------
// 64x64 block tile, K=128. Memory-bound by design (201 MB traffic).
__global__ __launch_bounds__(256) void k1a_gemm(const float* __restrict__ x,
                                                const float* __restrict__ W1,
                                                float* __restrict__ hpre,
                                                float* __restrict__ ws) {
  __shared__ __align__(16) float As[32][72];
  __shared__ __align__(16) float Bs[32][64];
  __shared__ float cs[16][68];
  const int t = threadIdx.x;
  const int row0 = blockIdx.x * 64;
  const int tx = t & 15, ty = t >> 4;
  float acc[4][4];
#pragma unroll
  for (int i = 0; i < 4; i++)
#pragma unroll
    for (int j = 0; j < 4; j++) acc[i][j] = 0.f;

  for (int k0 = 0; k0 < CIN; k0 += 32) {
    __syncthreads();
    {  // A tile: 64 rows x 32 k (transposed into [k][m])
      int r = t >> 2;
      int c = (t & 3) * 8;
      const float* src = &x[(size_t)(row0 + r) * CIN + k0 + c];
      float4 a0 = *(const float4*)src;
      float4 a1 = *(const float4*)(src + 4);
      As[c + 0][r] = a0.x; As[c + 1][r] = a0.y; As[c + 2][r] = a0.z; As[c + 3][r] = a0.w;
      As[c + 4][r] = a1.x; As[c + 5][r] = a1.y; As[c + 6][r] = a1.z; As[c + 7][r] = a1.w;
    }
    {  // B tile: 32 k x 64 cols
      int kk = t >> 3;
      int c = (t & 7) * 8;
      const float* B = &W1[(size_t)(k0 + kk) * D2 + c];
      *(float4*)&Bs[kk][c] = *(const float4*)B;
      *(float4*)&Bs[kk][c + 4] = *(const float4*)(B + 4);
    }
    __syncthreads();
#pragma unroll
    for (int k = 0; k < 32; ++k) {
      float4 av = *(const float4*)&As[k][ty * 4];
      float4 bv = *(const float4*)&Bs[k][tx * 4];
      float a[4] = {av.x, av.y, av.z, av.w};
      float b[4] = {bv.x, bv.y, bv.z, bv.w};
#pragma unroll
      for (int i = 0; i < 4; i++)
#pragma unroll
        for (int j = 0; j < 4; j++) acc[i][j] = fmaf(a[i], b[j], acc[i][j]);
    }
  }
#pragma unroll
  for (int i = 0; i < 4; i++) {
    int r = row0 + ty * 4 + i;
    *(float4*)&hpre[(size_t)r * D2 + tx * 4] =
        make_float4(acc[i][0], acc[i][1], acc[i][2], acc[i][3]);
  }
  // fused BN1 column stats over this block's 64 rows
  __syncthreads();
#pragma unroll
  for (int j = 0; j < 4; j++)
    cs[ty][tx * 4 + j] = acc[0][j] + acc[1][j] + acc[2][j] + acc[3][j];
  __syncthreads();
  if (t < 64) {
    float s = 0.f;
#pragma unroll
    for (int w = 0; w < 16; w++) s += cs[w][t];
    atomicAdd(&ws[WS_BN1_SUM + t], s);
  }
  __syncthreads();
#pragma unroll
  for (int j = 0; j < 4; j++) {
    float q = 0.f;
#pragma unroll
    for (int i = 0; i < 4; i++) q = fmaf(acc[i][j], acc[i][j], q);
    cs[ty][tx * 4 + j] = q;
  }
  __syncthreads();
  if (t < 64) {
    float q = 0.f;
#pragma unroll
    for (int w = 0; w < 16; w++) q += cs[w][t];
    atomicAdd(&ws[WS_BN1_SQ + t], q);
  }
}

// ---------------- k2b: finalize BN1 scale/shift ----------------
__global__ void k2b_fin1(const float* __restrict__ g1, const float* __restrict__ b1,
                         float* __restrict__ ws) {
  int c = threadIdx.x;  // 64
  float m = ws[WS_BN1_SUM + c] * (1.f / NPTS);
  float v = ws[WS_BN1_SQ + c] * (1.f / NPTS) - m * m;
  float sc = g1[c] / sqrtf(v + BEPS);
  ws[WS_DERIV + D_S1 + c] = sc;
  ws[WS_DERIV + D_T1 + c] = b1[c] - m * sc;
}

// ---------------- k3a: filter pairs; build lists; zero active kppre rows ------
__global__ __launch_bounds__(256) void k3a_filter(const int* __restrict__ idx,
                                                  const float* __restrict__ pos,
                                                  const float* __restrict__ kpts,
                                                  float* __restrict__ ws, int cap) {
  __shared__ float kp[NKP * 3];
  int t = threadIdx.x;
  if (t < NKP * 3) kp[t] = kpts[t];
  __syncthreads();
  int id = blockIdx.x * 256 + t;
  int p = id >> 4;
  int ia = idx[id];
  if (ia >= NPTS) return;  // shadow neighbor
  float px = pos[p * 3 + 0], py = pos[p * 3 + 1], pz = pos[p * 3 + 2];
  float dx = pos[ia * 3 + 0] - px, dy = pos[ia * 3 + 1] - py, dz = pos[ia * 3 + 2] - pz;
  const float thr = PINF * PINF * 1.0001f;
  bool act = false;
#pragma unroll 1
  for (int k = 0; k < NKP; k++) {
    float ex = dx - kp[k * 3 + 0], ey = dy - kp[k * 3 + 1], ez = dz - kp[k * 3 + 2];
    float s = fmaf(ex, ex, fmaf(ey, ey, ez * ez));
    act = act || (s < thr);
  }
  if (act) {
    int slot = atomicAdd((int*)&ws[WS_PAIRCNT], 1);
    if (slot < cap) {
      int* pairs = (int*)&ws[WS_PAIRS];
      pairs[2 * slot] = p;
      pairs[2 * slot + 1] = ia;
    }
    int* flags = (int*)&ws[WS_FLAGS];
    if (atomicExch(&flags[p], 1) == 0) {
      int ps = atomicAdd((int*)&ws[WS_PTCNT], 1);
      ((int*)&ws[WS_PLIST])[ps] = p;
      // first toucher zeroes this point's kppre row (k3b runs in a later kernel)
      float4* row = (float4*)&ws[WS_KPPRE + (size_t)p * D2];
      float4 z = make_float4(0.f, 0.f, 0.f, 0.f);
#pragma unroll
      for (int j = 0; j < 16; j++) row[j] = z;
    }
  }
}

// ---------------- k3b: process active pairs ----------------
// Register-light: wave-uniform active-k bitmask, unroll-1 loops (the 15x
// unroll in r1/r3 spilled ~6 KB/thread of scratch), pointer-bump matvec.
__global__ __launch_bounds__(256) void k3b_active(const float* __restrict__ pos,
                                                  const float* __restrict__ kpts,
                                                  const float* __restrict__ kpw,
                                                  float* __restrict__ ws, int cap) {
  __shared__ float kp[NKP * 3];
  const int t = threadIdx.x;
  if (t < NKP * 3) kp[t] = kpts[t];
  __syncthreads();
  const int l = t & 63;
  const int g = blockIdx.x * 4 + (t >> 6);
  const int nw = gridDim.x * 4;
  const int* pairs = (const int*)&ws[WS_PAIRS];
  int npairs = ((const int*)ws)[WS_PAIRCNT];
  if (npairs > cap) npairs = cap;
  const float* hpre = &ws[WS_HPRE];
  const float s1l = ws[WS_DERIV + D_S1 + l];
  const float t1l = ws[WS_DERIV + D_T1 + l];
  float* kppre = &ws[WS_KPPRE];
  const float invp = 1.f / PINF;
  const float r2 = PINF * PINF;

#pragma unroll 1
  for (int i = g; i < npairs; i += nw) {
    int p = pairs[2 * i], ia = pairs[2 * i + 1];
    float px = pos[p * 3 + 0], py = pos[p * 3 + 1], pz = pos[p * 3 + 2];
    float dx = pos[ia * 3 + 0] - px, dy = pos[ia * 3 + 1] - py, dz = pos[ia * 3 + 2] - pz;
    unsigned mask = 0;
#pragma unroll 1
    for (int k = 0; k < NKP; k++) {
      float ex = dx - kp[k * 3 + 0], ey = dy - kp[k * 3 + 1], ez = dz - kp[k * 3 + 2];
      float s = fmaf(ex, ex, fmaf(ey, ey, ez * ez));
      if (s < r2) mask |= (1u << k);
    }
    if (mask == 0) continue;  // filter-inflation marginal: exact-zero contribution
    float f = lrelu(fmaf(s1l, hpre[(size_t)ia * D2 + l], t1l));
    float accd = 0.f;
#pragma unroll 1
    while (mask) {
      int k = __ffs(mask) - 1;
      mask &= mask - 1;
      float ex = dx - kp[k * 3 + 0], ey = dy - kp[k * 3 + 1], ez = dz - kp[k * 3 + 2];
      float s = fmaf(ex, ex, fmaf(ey, ey, ez * ez));
      float wk = 1.f - sqrtf(s) * invp;  // > 0 by mask construction
      const float* kwk = kpw + ((size_t)k << 12) + l;
      float m0 = 0.f, m1 = 0.f, m2 = 0.f, m3 = 0.f;
#pragma unroll 1
      for (int c = 0; c < D2; c += 4) {
        float f0 = __shfl(f, c + 0), f1 = __shfl(f, c + 1);
        float f2 = __shfl(f, c + 2), f3 = __shfl(f, c + 3);
        m0 = fmaf(f0, kwk[0], m0);
        m1 = fmaf(f1, kwk[64], m1);
        m2 = fmaf(f2, kwk[128], m2);
        m3 = fmaf(f3, kwk[192], m3);
        kwk += 256;
      }
      accd = fmaf(wk, (m0 + m1) + (m2 + m3), accd);
    }
    atomicAdd(&kppre[(size_t)p * D2 + l], accd);
  }
}

// ---------------- k4: BN_kp stats over active rows (zeros elsewhere) ----------
__global__ __launch_bounds__(256) void k4_stats_kp(float* __restrict__ ws) {
  const int t = threadIdx.x;
  const int l = t & 63, wv = t >> 6;
  const int g = blockIdx.x * 4 + wv;
  const int nw = gridDim.x * 4;
  const int* plist = (const int*)&ws[WS_PLIST];
  int pcnt = ((const int*)ws)[WS_PTCNT];
  const float* kppre = &ws[WS_KPPRE];
  float s = 0.f, q = 0.f;
  for (int i = g; i < pcnt; i += nw) {
    float v = kppre[(size_t)plist[i] * D2 + l];
    s += v;
    q = fmaf(v, v, q);
  }
  __shared__ float red[4][64];
  red[wv][l] = s;
  __syncthreads();
  if (t < 64) atomicAdd(&ws[WS_KP_SUM + t], red[0][t] + red[1][t] + red[2][t] + red[3][t]);
  __syncthreads();
  red[wv][l] = q;
  __syncthreads();
  if (t < 64) atomicAdd(&ws[WS_KP_SQ + t], red[0][t] + red[1][t] + red[2][t] + red[3][t]);
}

// ---------------- k4b: finalize BN_kp; base z row; base u2 row ----------------
__global__ void k4b_fin_kp(const float* __restrict__ gkp, const float* __restrict__ bkp,
                           const float* __restrict__ W2, float* __restrict__ ws) {
  int t = threadIdx.x;  // 256
  __shared__ float zb[64];
  if (t < 64) {
    float m = ws[WS_KP_SUM + t] * (1.f / NPTS);
    float v = ws[WS_KP_SQ + t] * (1.f / NPTS) - m * m;
    float sc = gkp[t] / sqrtf(v + BEPS);
    float sh = bkp[t] - m * sc;
    ws[WS_DERIV + D_SKP + t] = sc;
    ws[WS_DERIV + D_TKP + t] = sh;
    float z = lrelu(sh);
    ws[WS_DERIV + D_ZB + t] = z;
    zb[t] = z;
  }
  __syncthreads();
  float u = 0.f;
  for (int c = 0; c < D2; c++) u = fmaf(zb[c], W2[(size_t)c * COUT + t], u);
  ws[WS_DERIV + D_BU2 + t] = u;
}

// ---------------- k5: BN2 stats centered on base row (wave per active point) --
__global__ __launch_bounds__(256) void k5_stats_u2(const float* __restrict__ W2,
                                                   float* __restrict__ ws) {
  const int t = threadIdx.x;
  const int l = t & 63, wv = t >> 6;
  const int g = blockIdx.x * 4 + wv;
  const int nw = gridDim.x * 4;
  const int* plist = (const int*)&ws[WS_PLIST];
  int pcnt = ((const int*)ws)[WS_PTCNT];
  const float* kppre = &ws[WS_KPPRE];
  const float skl = ws[WS_DERIV + D_SKP + l];
  const float tkl = ws[WS_DERIV + D_TKP + l];
  float bu[4], ds[4] = {0.f, 0.f, 0.f, 0.f}, dq[4] = {0.f, 0.f, 0.f, 0.f};
#pragma unroll
  for (int j = 0; j < 4; j++) bu[j] = ws[WS_DERIV + D_BU2 + j * 64 + l];

  for (int i = g; i < pcnt; i += nw) {
    int p = plist[i];
    float z = lrelu(fmaf(skl, kppre[(size_t)p * D2 + l], tkl));
    float u0 = 0.f, u1 = 0.f, u2 = 0.f, u3 = 0.f;
#pragma unroll
    for (int c = 0; c < D2; c++) {
      float zc = __shfl(z, c);
      const float* w2c = &W2[(size_t)c * COUT + l];
      u0 = fmaf(zc, w2c[0], u0);
      u1 = fmaf(zc, w2c[64], u1);
      u2 = fmaf(zc, w2c[128], u2);
      u3 = fmaf(zc, w2c[192], u3);
    }
    float du0 = u0 - bu[0], du1 = u1 - bu[1], du2 = u2 - bu[2], du3 = u3 - bu[3];
    ds[0] += du0; ds[1] += du1; ds[2] += du2; ds[3] += du3;
    dq[0] = fmaf(du0, du0, dq[0]); dq[1] = fmaf(du1, du1, dq[1]);
    dq[2] = fmaf(du2, du2, dq[2]); dq[3] = fmaf(du3, du3, dq[3]);
  }
  __shared__ float red[4][256];
#pragma unroll
  for (int j = 0; j < 4; j++) red[wv][j * 64 + l] = ds[j];
  __syncthreads();
  atomicAdd(&ws[WS_U2_DSUM + t], red[0][t] + red[1][t] + red[2][t] + red[3][t]);
  __syncthreads();
#pragma unroll
  for (int j = 0; j < 4; j++) red[wv][j * 64 + l] = dq[j];
  __syncthreads();
  atomicAdd(&ws[WS_U2_DSQ + t], red[0][t] + red[1][t] + red[2][t] + red[3][t]);
}

// ---------------- k6: finalize BN2; final base output row ----------------
__global__ void k6_fin2(const float* __restrict__ g2, const float* __restrict__ b2,
                        float* __restrict__ ws) {
  int t = threadIdx.x;  // 256
  float bu = ws[WS_DERIV + D_BU2 + t];
  float dm = ws[WS_U2_DSUM + t] * (1.f / NPTS);
  float dv = ws[WS_U2_DSQ + t] * (1.f / NPTS) - dm * dm;
  float mean = bu + dm;
  float sc = g2[t] / sqrtf(dv + BEPS);
  float sh = b2[t] - mean * sc;
  ws[WS_DERIV + D_S2 + t] = sc;
  ws[WS_DERIV + D_T2 + t] = sh;
  ws[WS_DERIV + D_FB + t] = lrelu(fmaf(sc, bu, sh));
}

// ---------------- k7g: out = x @ Wsc + fb  (single pass, no flags) ----------
__global__ __launch_bounds__(256) void k7g_gemm(const float* __restrict__ x,
                                                const float* __restrict__ Wsc,
                                                float* __restrict__ out,
                                                const float* __restrict__ ws) {
  __shared__ __align__(16) float As[32][72];
  __shared__ __align__(16) float Bs[4][32][64];
  const int t = threadIdx.x;
  const int row0 = blockIdx.x * 64;
  const int tx = t & 15, ty = t >> 4;
  float acc[4][4][4];
#pragma unroll
  for (int j5 = 0; j5 < 4; j5++)
#pragma unroll
    for (int i = 0; i < 4; i++)
#pragma unroll
      for (int j = 0; j < 4; j++) acc[j5][i][j] = 0.f;

  for (int k0 = 0; k0 < CIN; k0 += 32) {
    __syncthreads();
    {
      int r = t >> 2;
      int c = (t & 3) * 8;
      const float* src = &x[(size_t)(row0 + r) * CIN + k0 + c];
      float4 a0 = *(const float4*)src;
      float4 a1 = *(const float4*)(src + 4);
      As[c + 0][r] = a0.x; As[c + 1][r] = a0.y; As[c + 2][r] = a0.z; As[c + 3][r] = a0.w;
      As[c + 4][r] = a1.x; As[c + 5][r] = a1.y; As[c + 6][r] = a1.z; As[c + 7][r] = a1.w;
    }
    {
      int kk = t >> 3;
      int c = (t & 7) * 8;
#pragma unroll
      for (int j5 = 0; j5 < 4; j5++) {
        const float* B = &Wsc[(size_t)(k0 + kk) * COUT + j5 * 64 + c];
        *(float4*)&Bs[j5][kk][c] = *(const float4*)B;
        *(float4*)&Bs[j5][kk][c + 4] = *(const float4*)(B + 4);
      }
    }
    __syncthreads();
#pragma unroll
    for (int k = 0; k < 32; ++k) {
      float4 av = *(const float4*)&As[k][ty * 4];
      float a[4] = {av.x, av.y, av.z, av.w};
#pragma unroll
      for (int j5 = 0; j5 < 4; j5++) {
        float4 bv = *(const float4*)&Bs[j5][k][tx * 4];
        float b[4] = {bv.x, bv.y, bv.z, bv.w};
#pragma unroll
        for (int i = 0; i < 4; i++)
#pragma unroll
          for (int j = 0; j < 4; j++) acc[j5][i][j] = fmaf(a[i], b[j], acc[j5][i][j]);
      }
    }
  }
  float4 fbv[4];
#pragma unroll
  for (int j5 = 0; j5 < 4; j5++)
    fbv[j5] = *(const float4*)&ws[WS_DERIV + D_FB + j5 * 64 + tx * 4];
#pragma unroll
  for (int i = 0; i < 4; i++) {
    int r = row0 + ty * 4 + i;
#pragma unroll
    for (int j5 = 0; j5 < 4; j5++) {
      float4 o = make_float4(acc[j5][i][0] + fbv[j5].x, acc[j5][i][1] + fbv[j5].y,
                             acc[j5][i][2] + fbv[j5].z, acc[j5][i][3] + fbv[j5].w);
      *(float4*)&out[(size_t)r * COUT + j5 * 64 + tx * 4] = o;
    }
  }
}

// ---------------- k7a: active rows  out[p] += (lrelu(bn2(u2_p)) - fb) --------
__global__ __launch_bounds__(256) void k7a_active(const float* __restrict__ W2,
                                                  float* __restrict__ out,
                                                  float* __restrict__ ws) {
  const int t = threadIdx.x;
  const int l = t & 63;
  const int g = blockIdx.x * 4 + (t >> 6);
  const int nw = gridDim.x * 4;
  const int* plist = (const int*)&ws[WS_PLIST];
  int pcnt = ((const int*)ws)[WS_PTCNT];
  const float* kppre = &ws[WS_KPPRE];
  const float skl = ws[WS_DERIV + D_SKP + l];
  const float tkl = ws[WS_DERIV + D_TKP + l];
  float s2[4], t2[4], fb[4];
#pragma unroll
  for (int j = 0; j < 4; j++) {
    s2[j] = ws[WS_DERIV + D_S2 + j * 64 + l];
    t2[j] = ws[WS_DERIV + D_T2 + j * 64 + l];
    fb[j] = ws[WS_DERIV + D_FB + j * 64 + l];
  }
  for (int i = g; i < pcnt; i += nw) {
    int p = plist[i];
    float z = lrelu(fmaf(skl, kppre[(size_t)p * D2 + l], tkl));
    float u0 = 0.f, u1 = 0.f, u2 = 0.f, u3 = 0.f;
#pragma unroll
    for (int c = 0; c < D2; c++) {
      float zc = __shfl(z, c);
      const float* w2c = &W2[(size_t)c * COUT + l];
      u0 = fmaf(zc, w2c[0], u0);
      u1 = fmaf(zc, w2c[64], u1);
      u2 = fmaf(zc, w2c[128], u2);
      u3 = fmaf(zc, w2c[192], u3);
    }
    float* op = &out[(size_t)p * COUT + l];
    op[0]   += lrelu(fmaf(s2[0], u0, t2[0])) - fb[0];
    op[64]  += lrelu(fmaf(s2[1], u1, t2[1])) - fb[1];
    op[128] += lrelu(fmaf(s2[2], u2, t2[2])) - fb[2];
    op[192] += lrelu(fmaf(s2[3], u3, t2[3])) - fb[3];
  }
}

// ---------------- launch ----------------
extern "C" void kernel_launch(void* const* d_in, const int* in_sizes, int n_in,
                              void* d_out, int out_size, void* d_ws, size_t ws_size,
                              hipStream_t stream) {
  const float* x    = (const float*)d_in[0];
  const float* pos  = (const float*)d_in[1];
  const int*   idx  = (const int*)d_in[2];
  const float* W1   = (const float*)d_in[3];
  const float* g1   = (const float*)d_in[4];
  const float* b1   = (const float*)d_in[5];
  const float* kpts = (const float*)d_in[6];
  const float* kpw  = (const float*)d_in[7];
  const float* gkp  = (const float*)d_in[8];
  const float* bkp  = (const float*)d_in[9];
  const float* W2   = (const float*)d_in[10];
  const float* g2   = (const float*)d_in[11];
  const float* b2   = (const float*)d_in[12];
  const float* Wsc  = (const float*)d_in[13];
  float* out = (float*)d_out;
  float* ws = (float*)d_ws;

  long long cap_ll = ((long long)(ws_size / 4) - (long long)WS_PAIRS) / 2;
  if (cap_ll < 0) cap_ll = 0;
  if (cap_ll > (long long)NPTS * NNB) cap_ll = (long long)NPTS * NNB;
  int cap = (int)cap_ll;

  k0_zero<<<256, 256, 0, stream>>>(ws);
  k1a_gemm<<<NPTS / 64, 256, 0, stream>>>(x, W1, &ws[WS_HPRE], ws);
  k2b_fin1<<<1, 64, 0, stream>>>(g1, b1, ws);
  k3a_filter<<<NPTS * NNB / 256, 256, 0, stream>>>(idx, pos, kpts, ws, cap);
  k3b_active<<<512, 256, 0, stream>>>(pos, kpts, kpw, ws, cap);
  k4_stats_kp<<<256, 256, 0, stream>>>(ws);
  k4b_fin_kp<<<1, 256, 0, stream>>>(gkp, bkp, W2, ws);
  k5_stats_u2<<<512, 256, 0, stream>>>(W2, ws);
  k6_fin2<<<1, 256, 0, stream>>>(g2, b2, ws);
  k7g_gemm<<<NPTS / 64, 256, 0, stream>>>(x, Wsc, out, ws);
  k7a_active<<<512, 256, 0, stream>>>(W2, out, ws);
}